// Round 3
// baseline (64.537 us; speedup 1.0000x reference)
//
#include <hip/hip_runtime.h>
#include <math.h>

// LIFNeuronFDE: fractional-order LIF with Grunwald-Letnikov memory.
//   v^{k+1} = h^beta * (I_k - v^k)/tau - sum_{j=0}^{k} c_{k+1-j} v^{(j)}
//   spike_k = sigmoid(scale * (v^{k+1} - V_th))
// Constants: tau=0.5, thresh=1.0, scale=5.0, beta=0.5, h=1.0 => h^beta=1, 1/tau=2.
// T=32, B=32, N=32768.
//
// R2 lesson: VGPR_Count=40 proved the compiler left h[] in scratch (outer
// #pragma unroll not honored -> runtime-indexed array -> private memory,
// ~4.4GB L2 scratch traffic, 96us). Fix: template-recursive steps so EVERY
// h[] index is a compile-time literal -> mem2reg promotes history to
// registers. Arithmetic token-identical to R2 (fp64, ascending j, same fma)
// -> bitwise-identical output (absmax margin is small: 0.0176/0.02).

#define T_STEPS 32
#define BN (32 * 32768)              // B*N = 1,048,576 elements

struct Coef { double c[T_STEPS + 1]; };

constexpr Coef make_coef() {
    Coef r{};
    r.c[0] = 1.0;
    double cur = 1.0;
    for (int j = 1; j <= T_STEPS; ++j) {
        cur *= (1.0 - 1.5 / (double)j);   // (1 - (1+beta)/j), beta=0.5
        r.c[j] = cur;
    }
    return r;
}

constexpr Coef CF = make_coef();

template<int K>
__device__ __forceinline__ void fde_step(double (&h)[T_STEPS], double& v,
                                         const float* __restrict__ I,
                                         float* __restrict__ out,
                                         const int idx)
{
    h[K] = v;   // static index

    // GL memory term: sum_{j=0}^{K} c[K+1-j] * h[j] — all indices literal
    double m = 0.0;
    #pragma unroll
    for (int j = 0; j <= K; ++j) {
        m = fma(CF.c[K + 1 - j], h[j], m);
    }

    const float Ik = I[(size_t)K * BN + idx];

    // h^beta * (I - v)/tau - mem  with h^beta=1, 1/tau=2
    v = 2.0 * ((double)Ik - v) - m;

    // spike = sigmoid(5*(v - 1))
    const float a = (float)(-5.0 * (v - 1.0));
    out[(size_t)K * BN + idx] = 1.0f / (1.0f + __expf(a));
}

template<int K>
__device__ __forceinline__ void fde_run(double (&h)[T_STEPS], double& v,
                                        const float* __restrict__ I,
                                        float* __restrict__ out,
                                        const int idx)
{
    if constexpr (K < T_STEPS) {
        fde_step<K>(h, v, I, out, idx);
        fde_run<K + 1>(h, v, I, out, idx);
    }
}

__global__ __launch_bounds__(256) void lif_fde_kernel(
    const float* __restrict__ I,
    const float* __restrict__ v0,
    float* __restrict__ out)
{
    const int idx = blockIdx.x * blockDim.x + threadIdx.x;   // [0, BN)

    double v = (double)v0[idx];
    double h[T_STEPS];   // promoted to registers (all indices static)

    fde_run<0>(h, v, I, out, idx);
}

extern "C" void kernel_launch(void* const* d_in, const int* in_sizes, int n_in,
                              void* d_out, int out_size, void* d_ws, size_t ws_size,
                              hipStream_t stream) {
    const float* I  = (const float*)d_in[0];   // (T, B, N) fp32
    const float* v0 = (const float*)d_in[1];   // (B, N) fp32
    float* out = (float*)d_out;                // (T, B, N) fp32

    dim3 block(256);
    dim3 grid(BN / 256);                       // 4096 blocks, exact fit
    lif_fde_kernel<<<grid, block, 0, stream>>>(I, v0, out);
}

// Round 4
// 62.230 us; speedup vs baseline: 1.0371x; 1.0371x over previous
//
#include <hip/hip_runtime.h>
#include <math.h>

// LIFNeuronFDE: fractional-order LIF with Grunwald-Letnikov memory.
//   v^{k+1} = h^beta * (I_k - v^k)/tau - sum_{j=0}^{k} c_{k+1-j} v^{(j)}
//   spike_k = sigmoid(scale * (v^{k+1} - V_th))
// Constants: tau=0.5, thresh=1.0, scale=5.0, beta=0.5, h=1.0 => h^beta=1, 1/tau=2.
// T=32, B=32, N=32768.
//
// R3 lesson: VGPR_Count=40 + occupancy 55% + zero HBM scratch traffic =>
// allocator heuristically capped arch VGPRs and spilled fp64 history to
// AGPRs (accvgpr moves on all 528 history reads, no load hoisting).
// Fixes (both numerics-free):
//  1) __launch_bounds__(256, 2): VGPR cap 256 -> no forced AGPR spill.
//  2) Scatter/accumulator form of the GL convolution: A[t] += c[t+1-j]*v_j
//     as each v_j is produced; m_k = A[k]. Same fma ops on the same
//     accumulator in the same ascending-j order as the gather version ->
//     BITWISE-identical output (absmax margin is thin: 0.0176/0.02).
//     Bonus: no stored history, A[] liveness declines, per-step FMAs are
//     mutually independent (no serial chain).

#define T_STEPS 32
#define BN (32 * 32768)              // B*N = 1,048,576 elements

struct Coef { double c[T_STEPS + 1]; };

constexpr Coef make_coef() {
    Coef r{};
    r.c[0] = 1.0;
    double cur = 1.0;
    for (int j = 1; j <= T_STEPS; ++j) {
        cur *= (1.0 - 1.5 / (double)j);   // (1 - (1+beta)/j), beta=0.5
        r.c[j] = cur;
    }
    return r;
}

constexpr Coef CF = make_coef();

// Step K: v currently holds v^{(K)}.
//  - scatter v^{(K)}'s contribution into A[t] for t=K..T-1 (coef c[t+1-K])
//  - m_K = A[K] is now complete (received j=0..K in ascending order)
//  - v <- 2*(I_K - v) - m ; spike = sigmoid(5*(v-1))
template<int K>
__device__ __forceinline__ void fde_step(double (&A)[T_STEPS], double& v,
                                         const float* __restrict__ I,
                                         float* __restrict__ out,
                                         const int idx)
{
    #pragma unroll
    for (int t = K; t < T_STEPS; ++t) {
        A[t] = fma(CF.c[t + 1 - K], v, A[t]);   // independent FMAs, literal idx
    }

    const double m = A[K];
    const float Ik = I[(size_t)K * BN + idx];

    v = 2.0 * ((double)Ik - v) - m;

    const float a = (float)(-5.0 * (v - 1.0));
    out[(size_t)K * BN + idx] = 1.0f / (1.0f + __expf(a));
}

template<int K>
__device__ __forceinline__ void fde_run(double (&A)[T_STEPS], double& v,
                                        const float* __restrict__ I,
                                        float* __restrict__ out,
                                        const int idx)
{
    if constexpr (K < T_STEPS) {
        fde_step<K>(A, v, I, out, idx);
        fde_run<K + 1>(A, v, I, out, idx);
    }
}

__global__ __launch_bounds__(256, 2) void lif_fde_kernel(
    const float* __restrict__ I,
    const float* __restrict__ v0,
    float* __restrict__ out)
{
    const int idx = blockIdx.x * blockDim.x + threadIdx.x;   // [0, BN)

    double v = (double)v0[idx];

    double A[T_STEPS];   // running GL accumulators; A[t] dies after step t
    #pragma unroll
    for (int t = 0; t < T_STEPS; ++t) A[t] = 0.0;

    fde_run<0>(A, v, I, out, idx);
}

extern "C" void kernel_launch(void* const* d_in, const int* in_sizes, int n_in,
                              void* d_out, int out_size, void* d_ws, size_t ws_size,
                              hipStream_t stream) {
    const float* I  = (const float*)d_in[0];   // (T, B, N) fp32
    const float* v0 = (const float*)d_in[1];   // (B, N) fp32
    float* out = (float*)d_out;                // (T, B, N) fp32

    dim3 block(256);
    dim3 grid(BN / 256);                       // 4096 blocks, exact fit
    lif_fde_kernel<<<grid, block, 0, stream>>>(I, v0, out);
}

// Round 5
// 61.231 us; speedup vs baseline: 1.0540x; 1.0163x over previous
//
#include <hip/hip_runtime.h>
#include <math.h>

// LIFNeuronFDE: fractional-order LIF with Grunwald-Letnikov memory.
//   v^{k+1} = 2*(I_k - v^k) - sum_{j=0}^{k} c_{k+1-j} v^{(j)},  v^{(0)} = v0
//   spike_k = sigmoid(5*(v^{k+1} - 1))
// T=32, B=32, N=32768.
//
// R1-R4 lesson: the sequential form is latency-bound (~90us even when input
// is L3-resident): v_{k+1} depends on v_k, and each I_k load feeds its use
// immediately, so waves stall ~900cy per step regardless of occupancy.
//
// Fix: the recurrence is LINEAR. Precompute at compile time (constexpr,
// fp64, by running the recurrence on coefficient vectors):
//     v_{k+1} = b[k]*v0 + sum_{j<=k} A[k][j] * I_j
// This kills the runtime dependence chain entirely: 32 independent loads
// issued upfront (one pipelined latency hit), then 32 independent fp64
// triangular dot products. Dot products stay fp64 because |A| grows to ~1e6
// (growing mode |lambda|~1.57 ^32); fp32 accumulation would inject O(0.1)
// error near the sigmoid threshold. fp64 reshuffle error ~5e-8 -> absmax
// unchanged (0.01758 < 0.02 threshold).

#define T_STEPS 32
#define BN (32 * 32768)              // B*N = 1,048,576 elements

struct LinMap {
    double a[T_STEPS][T_STEPS];      // a[k][j]: coeff of I_j in v_{k+1} (j<=k)
    double b[T_STEPS];               // b[k]:    coeff of v0  in v_{k+1}
};

constexpr LinMap make_linmap() {
    // GL coefficients: c_0=1, c_j = (1 - 1.5/j) c_{j-1}
    double c[T_STEPS + 1] = {};
    c[0] = 1.0;
    for (int j = 1; j <= T_STEPS; ++j) c[j] = c[j - 1] * (1.0 - 1.5 / (double)j);

    // vc[k][m]: coefficient of basis element m in v_k.
    // basis: m=0 -> v0, m=1+j -> I_j
    double vc[T_STEPS + 1][T_STEPS + 1] = {};
    vc[0][0] = 1.0;

    LinMap r{};
    for (int k = 0; k < T_STEPS; ++k) {
        // v_{k+1} = 2*I_k - 2*v_k - sum_{j=0}^{k} c[k+1-j] * v_j
        for (int m = 0; m <= T_STEPS; ++m) {
            double acc = -2.0 * vc[k][m];
            for (int j = 0; j <= k; ++j) acc -= c[k + 1 - j] * vc[j][m];
            vc[k + 1][m] = acc;
        }
        vc[k + 1][1 + k] += 2.0;

        r.b[k] = vc[k + 1][0];
        for (int j = 0; j < T_STEPS; ++j) r.a[k][j] = vc[k + 1][1 + j];
    }
    return r;
}

constexpr LinMap CM = make_linmap();

__global__ __launch_bounds__(256, 2) void lif_fde_kernel(
    const float* __restrict__ I,
    const float* __restrict__ v0,
    float* __restrict__ out)
{
    const int idx = blockIdx.x * blockDim.x + threadIdx.x;   // [0, BN)

    // Issue ALL loads upfront — independent, they pipeline into one
    // latency hit instead of 32 serial ones.
    double Id[T_STEPS];
    #pragma unroll
    for (int k = 0; k < T_STEPS; ++k) {
        Id[k] = (double)I[(size_t)k * BN + idx];
    }
    const double v0d = (double)v0[idx];

    #pragma unroll
    for (int k = 0; k < T_STEPS; ++k) {
        double s = CM.b[k] * v0d;
        #pragma unroll
        for (int j = 0; j <= k; ++j) {
            s = fma(CM.a[k][j], Id[j], s);
        }
        // spike = sigmoid(5*(v_{k+1} - 1))
        const float a = (float)(-5.0 * (s - 1.0));
        out[(size_t)k * BN + idx] = 1.0f / (1.0f + __expf(a));
    }
}

extern "C" void kernel_launch(void* const* d_in, const int* in_sizes, int n_in,
                              void* d_out, int out_size, void* d_ws, size_t ws_size,
                              hipStream_t stream) {
    const float* I  = (const float*)d_in[0];   // (T, B, N) fp32
    const float* v0 = (const float*)d_in[1];   // (B, N) fp32
    float* out = (float*)d_out;                // (T, B, N) fp32

    dim3 block(256);
    dim3 grid(BN / 256);                       // 4096 blocks, exact fit
    lif_fde_kernel<<<grid, block, 0, stream>>>(I, v0, out);
}

// Round 6
// 55.738 us; speedup vs baseline: 1.1579x; 1.0985x over previous
//
#include <hip/hip_runtime.h>
#include <math.h>

// LIFNeuronFDE: fractional-order LIF with Grunwald-Letnikov memory.
//   v^{k+1} = 2*(I_k - v^k) - sum_{j=0}^{k} c_{k+1-j} v^{(j)},  v^{(0)} = v0
//   spike_k = sigmoid(5*(v^{k+1} - 1))
// T=32, B=32, N=32768.
//
// R5 lesson: killing the serial chain did NOT move the time; bench ranking
// shows access WIDTH is the live lever (R1 float2 56.5us beats all dword
// variants 61-65us). This round: linear-map form (v_{k+1} = b[k]*v0 +
// sum_j A[k][j] I_j, constexpr fp64 matrices) + 2 elems/thread with float2
// (dwordx2) loads/stores. Staged I kept in fp32 (exact, input dtype) and
// converted to fp64 at use -> 64 staging VGPRs instead of 128. fp64 fma
// sequence per element token-identical to R5 -> bitwise-identical output
// (absmax margin is thin: 0.0176/0.02).

#define T_STEPS 32
#define BN (32 * 32768)              // B*N = 1,048,576 elements
#define PAIRS (BN / 2)               // 524,288 float2 work items

struct LinMap {
    double a[T_STEPS][T_STEPS];      // a[k][j]: coeff of I_j in v_{k+1} (j<=k)
    double b[T_STEPS];               // b[k]:    coeff of v0  in v_{k+1}
};

constexpr LinMap make_linmap() {
    // GL coefficients: c_0=1, c_j = (1 - 1.5/j) c_{j-1}
    double c[T_STEPS + 1] = {};
    c[0] = 1.0;
    for (int j = 1; j <= T_STEPS; ++j) c[j] = c[j - 1] * (1.0 - 1.5 / (double)j);

    // vc[k][m]: coefficient of basis element m in v_k (m=0 -> v0, m=1+j -> I_j)
    double vc[T_STEPS + 1][T_STEPS + 1] = {};
    vc[0][0] = 1.0;

    LinMap r{};
    for (int k = 0; k < T_STEPS; ++k) {
        // v_{k+1} = 2*I_k - 2*v_k - sum_{j=0}^{k} c[k+1-j] * v_j
        for (int m = 0; m <= T_STEPS; ++m) {
            double acc = -2.0 * vc[k][m];
            for (int j = 0; j <= k; ++j) acc -= c[k + 1 - j] * vc[j][m];
            vc[k + 1][m] = acc;
        }
        vc[k + 1][1 + k] += 2.0;

        r.b[k] = vc[k + 1][0];
        for (int j = 0; j < T_STEPS; ++j) r.a[k][j] = vc[k + 1][1 + j];
    }
    return r;
}

constexpr LinMap CM = make_linmap();

// Row K: s = b[K]*v0 + sum_{j=0}^{K} a[K][j]*I_j (fp64, ascending j),
// then spike = sigmoid(5*(s-1)). All If[] indices are compile-time literals.
template<int K>
__device__ __forceinline__ void fde_rows(const float2 (&If)[T_STEPS],
                                         const double v0x, const double v0y,
                                         float2* __restrict__ out2,
                                         const int idx)
{
    if constexpr (K < T_STEPS) {
        double sx = CM.b[K] * v0x;
        double sy = CM.b[K] * v0y;
        #pragma unroll
        for (int j = 0; j <= K; ++j) {
            sx = fma(CM.a[K][j], (double)If[j].x, sx);
            sy = fma(CM.a[K][j], (double)If[j].y, sy);
        }
        const float ax = (float)(-5.0 * (sx - 1.0));
        const float ay = (float)(-5.0 * (sy - 1.0));
        out2[(size_t)K * PAIRS + idx] =
            make_float2(1.0f / (1.0f + __expf(ax)), 1.0f / (1.0f + __expf(ay)));

        fde_rows<K + 1>(If, v0x, v0y, out2, idx);
    }
}

__global__ __launch_bounds__(256) void lif_fde_kernel(
    const float* __restrict__ I,
    const float* __restrict__ v0,
    float* __restrict__ out)
{
    const int idx = blockIdx.x * blockDim.x + threadIdx.x;   // [0, PAIRS)

    const float2* __restrict__ I2   = (const float2*)I;
    const float2* __restrict__ v02  = (const float2*)v0;
    float2* __restrict__       out2 = (float2*)out;

    // Stage all of I for this pair in fp32 registers (exact), issued as 32
    // independent dwordx2 loads -> one pipelined latency hit.
    float2 If[T_STEPS];
    #pragma unroll
    for (int k = 0; k < T_STEPS; ++k) {
        If[k] = I2[(size_t)k * PAIRS + idx];
    }

    const float2 v0f = v02[idx];
    const double v0x = (double)v0f.x;
    const double v0y = (double)v0f.y;

    fde_rows<0>(If, v0x, v0y, out2, idx);
}

extern "C" void kernel_launch(void* const* d_in, const int* in_sizes, int n_in,
                              void* d_out, int out_size, void* d_ws, size_t ws_size,
                              hipStream_t stream) {
    const float* I  = (const float*)d_in[0];   // (T, B, N) fp32
    const float* v0 = (const float*)d_in[1];   // (B, N) fp32
    float* out = (float*)d_out;                // (T, B, N) fp32

    dim3 block(256);
    dim3 grid(PAIRS / 256);                    // 2048 blocks, exact fit
    lif_fde_kernel<<<grid, block, 0, stream>>>(I, v0, out);
}